// Round 5
// baseline (3858.516 us; speedup 1.0000x reference)
//
#include <hip/hip_runtime.h>

#define N_NODES 50000
#define MPAD    50048           // N_NODES rounded up to 128
#define IN_F    64
#define HIDDEN  512
#define N_EDGES 160000
#define N_TRAIN 80000
#define N_CLASS 7
#define BN_EPS  1e-5f

#define MT      (MPAD / 128)    // 391 m-tiles (K=64 kernel grid)
#define NT      4               // 128-col n-tiles
#define FULLGRP ((MT / 8) * 32) // 1536
#define NBLK    ((N_NODES + 255) / 256)   // 196 scan blocks

// 256x256 tiling for the K=512 GEMM
#define MT3     ((MPAD + 255) / 256)      // 196 m-tiles of 256 rows
#define NT3     2                         // 256-col n-tiles
#define FULLG3  ((MT3 / 8) * 16)          // 384 (24 groups of 8m x 2n)
#define NG3     (MT3 * NT3)               // 392 blocks

typedef short  bf16x8 __attribute__((ext_vector_type(8)));
typedef float  f32x4  __attribute__((ext_vector_type(4)));
typedef unsigned short ushort_t;

// ---- bf16 helpers (manual RNE; values are finite) -------------------------
__device__ __forceinline__ ushort_t f2b(float v) {
    union { float f; unsigned int u; } c; c.f = v;
    unsigned int x = c.u;
    unsigned int r = (x + 0x7FFFu + ((x >> 16) & 1u)) >> 16;
    return (ushort_t)r;
}
__device__ __forceinline__ float b2f(ushort_t b) {
    union { unsigned int u; float f; } c; c.u = ((unsigned int)b) << 16;
    return c.f;
}

// ---- async global->LDS, 16B per lane (dst = wave-uniform base + lane*16) --
__device__ __forceinline__ void async_copy16(const void* g, void* l) {
    __builtin_amdgcn_global_load_lds(
        (const __attribute__((address_space(1))) void*)g,
        (__attribute__((address_space(3))) void*)l, 16, 0, 0);
}

// ===========================================================================
// CSR build: zero -> histogram(dst) -> decoupled scan -> scatter src ids
// ===========================================================================
__global__ void zero_kernel(int* __restrict__ p, int n) {
    int i = blockIdx.x * blockDim.x + threadIdx.x;
    if (i < n) p[i] = 0;
}

__global__ void hist_kernel(const int* __restrict__ ei, int* __restrict__ deg) {
    int e = blockIdx.x * blockDim.x + threadIdx.x;
    if (e >= N_EDGES) return;
    atomicAdd(&deg[ei[N_EDGES + e]], 1);
}

__global__ __launch_bounds__(256) void blocksum_kernel(const int* __restrict__ deg,
                                                       int* __restrict__ bsum) {
    __shared__ int s[256];
    int i = blockIdx.x * 256 + threadIdx.x;
    s[threadIdx.x] = (i < N_NODES) ? deg[i] : 0;
    __syncthreads();
    for (int off = 128; off > 0; off >>= 1) {
        if (threadIdx.x < off) s[threadIdx.x] += s[threadIdx.x + off];
        __syncthreads();
    }
    if (threadIdx.x == 0) bsum[blockIdx.x] = s[0];
}

__global__ __launch_bounds__(256) void scanbsum_kernel(const int* __restrict__ bsum,
                                                       int* __restrict__ boff) {
    __shared__ int s[256];
    int tid = threadIdx.x;
    s[tid] = (tid < NBLK) ? bsum[tid] : 0;
    __syncthreads();
    for (int off = 1; off < 256; off <<= 1) {
        int t = (tid >= off) ? s[tid - off] : 0;
        __syncthreads();
        s[tid] += t;
        __syncthreads();
    }
    if (tid < NBLK) boff[tid] = (tid == 0) ? 0 : s[tid - 1];
}

__global__ __launch_bounds__(256) void rowptr_kernel(const int* __restrict__ deg,
                                                     const int* __restrict__ boff,
                                                     int* __restrict__ rowptr,
                                                     int* __restrict__ cursor) {
    __shared__ int s[256];
    int tid = threadIdx.x;
    int i = blockIdx.x * 256 + tid;
    int d = (i < N_NODES) ? deg[i] : 0;
    s[tid] = d;
    __syncthreads();
    for (int off = 1; off < 256; off <<= 1) {
        int t = (tid >= off) ? s[tid - off] : 0;
        __syncthreads();
        s[tid] += t;
        __syncthreads();
    }
    int incl = s[tid] + boff[blockIdx.x];
    if (i < N_NODES) {
        rowptr[i + 1] = incl;
        cursor[i] = incl - d;   // exclusive prefix = row start
    }
    if (i == 0) rowptr[0] = 0;
}

__global__ void scatter_kernel(const int* __restrict__ ei,
                               int* __restrict__ cursor, int* __restrict__ adj) {
    int e = blockIdx.x * blockDim.x + threadIdx.x;
    if (e >= N_EDGES) return;
    int src = ei[e], dst = ei[N_EDGES + e];
    int pos = atomicAdd(&cursor[dst], 1);
    adj[pos] = src;
}

// ===========================================================================
// Gather aggregation (CSR), fused scale + split-bf16 output.
// ===========================================================================
__global__ __launch_bounds__(256) void gather64_kernel(
    const float* __restrict__ x, const int* __restrict__ rowptr,
    const int* __restrict__ adj, const float* __restrict__ epsp,
    ushort_t* __restrict__ hi, ushort_t* __restrict__ lo) {
    int wave = threadIdx.x >> 6, lane = threadIdx.x & 63;
    int n = blockIdx.x * 4 + wave;
    if (n >= N_NODES) return;
    float s = 1.0f + *epsp;
    float sum = s * x[(size_t)n * IN_F + lane];
    int beg = rowptr[n], end = rowptr[n + 1];
    for (int k = beg; k < end; k++) {
        sum += x[(size_t)adj[k] * IN_F + lane];
    }
    ushort_t hb = f2b(sum);
    ushort_t lb = f2b(sum - b2f(hb));
    hi[(size_t)n * IN_F + lane] = hb;
    lo[(size_t)n * IN_F + lane] = lb;
}

__global__ __launch_bounds__(256) void gather512_kernel(
    const float* __restrict__ h, const int* __restrict__ rowptr,
    const int* __restrict__ adj, const float* __restrict__ epsp,
    ushort_t* __restrict__ hi, ushort_t* __restrict__ lo) {
    int wave = threadIdx.x >> 6, lane = threadIdx.x & 63;
    int n = blockIdx.x * 2 + (wave >> 1);
    if (n >= N_NODES) return;
    float s = 1.0f + *epsp;
    const int f = (wave & 1) * 256 + lane * 4;
    float4 a = *(const float4*)&h[(size_t)n * HIDDEN + f];
    float sum[4] = {s * a.x, s * a.y, s * a.z, s * a.w};
    int beg = rowptr[n], end = rowptr[n + 1];
    for (int k = beg; k < end; k++) {
        float4 b = *(const float4*)&h[(size_t)adj[k] * HIDDEN + f];
        sum[0] += b.x; sum[1] += b.y; sum[2] += b.z; sum[3] += b.w;
    }
    ushort_t h4[4], l4[4];
#pragma unroll
    for (int j = 0; j < 4; j++) {
        h4[j] = f2b(sum[j]);
        l4[j] = f2b(sum[j] - b2f(h4[j]));
    }
    *(ushort4*)&hi[(size_t)n * HIDDEN + f] = make_ushort4(h4[0], h4[1], h4[2], h4[3]);
    *(ushort4*)&lo[(size_t)n * HIDDEN + f] = make_ushort4(l4[0], l4[1], l4[2], l4[3]);
}

// ---------------------------------------------------------------------------
// Batched weight prep: all 6 W[K][512] fp32 -> Wt_hi/lo[512][K] bf16.
// ---------------------------------------------------------------------------
__global__ void wtrans_all_kernel(const float* __restrict__ w0,
                                  const float* __restrict__ w1,
                                  const float* __restrict__ w2,
                                  const float* __restrict__ w3,
                                  const float* __restrict__ w4,
                                  const float* __restrict__ w5,
                                  ushort_t* __restrict__ Wp) {
    const size_t WSMALL = (size_t)HIDDEN * IN_F;
    const size_t WBIG   = (size_t)HIDDEN * HIDDEN;
    int z = blockIdx.z;
    const float* W = (z == 0) ? w0 : (z == 1) ? w1 : (z == 2) ? w2
                   : (z == 3) ? w3 : (z == 4) ? w4 : w5;
    int K = (z == 0) ? IN_F : HIDDEN;
    size_t off_h = (z == 0) ? 0 : 2 * WSMALL + (size_t)(z - 1) * 2 * WBIG;
    ushort_t* Whi = Wp + off_h;
    ushort_t* Wlo = Whi + ((z == 0) ? WSMALL : WBIG);

    __shared__ float t[32][33];
    int tx = threadIdx.x & 31, ty = threadIdx.x >> 5;   // ty 0..7
    int nb = blockIdx.x * 32, kb = blockIdx.y * 32;
    if (kb >= K) return;
#pragma unroll
    for (int i = 0; i < 4; i++) {
        int k = kb + ty + i * 8;
        t[ty + i * 8][tx] = W[(size_t)k * HIDDEN + nb + tx];
    }
    __syncthreads();
#pragma unroll
    for (int i = 0; i < 4; i++) {
        int n = nb + ty + i * 8;
        int k = kb + tx;
        float v = t[tx][ty + i * 8];
        ushort_t hb = f2b(v);
        ushort_t lb = f2b(v - b2f(hb));
        Whi[(size_t)n * K + k] = hb;
        Wlo[(size_t)n * K + k] = lb;
    }
}

// ---------------------------------------------------------------------------
// K=512 split-bf16 GEMM, BM=256 x BN=256, 8 waves (512 thr), wave grid 2x4
// (each wave owns 128x64 output, acc[8][4] — same per-wave structure as R4,
// so VGPR stays ~124 and __launch_bounds__(512,4) keeps 2 blocks/CU).
// Schedule = R0's proven single-buffer 2-barrier loop (R1-R3: schedule is
// not the lever). Traffic model from R0/R4: time ≈ 0.24µs/MB (A panel, L3
// path — 102MB working set misses L2) + 0.078µs/MB (B weights, L2 path).
// BN=128->256 halves the expensive A re-reads: staged A 411->205 MB,
// B 205 MB; predicted ~80-95 µs/dispatch.
// ---------------------------------------------------------------------------
__global__ __launch_bounds__(512, 4) void gemm_split2x256_kernel(
    const ushort_t* __restrict__ Ahi, const ushort_t* __restrict__ Alo,
    const ushort_t* __restrict__ Bhi, const ushort_t* __restrict__ Blo,
    const float* __restrict__ bias,
    float* __restrict__ Cf, ushort_t* __restrict__ Chi, ushort_t* __restrict__ Clo,
    int mode,
    const float* __restrict__ bn_g, const float* __restrict__ bn_b,
    const float* __restrict__ bn_m, const float* __restrict__ bn_v) {
    const int K = HIDDEN;            // 512
    __shared__ ushort_t As_h[256 * 32];   // 16 KB
    __shared__ ushort_t As_l[256 * 32];   // 16 KB
    __shared__ ushort_t Bs_h[256 * 32];   // 16 KB
    __shared__ ushort_t Bs_l[256 * 32];   // 16 KB  -> 64 KB total

    const int tid  = threadIdx.x;
    const int wave = tid >> 6, lane = tid & 63;
    const int wm = wave >> 2, wn = wave & 3;   // 2x4 wave grid, 128x64 per wave
    const int quad = lane >> 4, r = lane & 15;

    int idx = blockIdx.x, m_t, n_t;
    if (idx < FULLG3) {                 // groups of 8 m-tiles x 2 n-tiles
        m_t = (idx >> 4) * 8 + (idx & 7);
        n_t = (idx >> 3) & 1;
    } else {
        int t2 = idx - FULLG3;          // tail: m-tiles 192..195 x 2
        m_t = 192 + (t2 >> 1);
        n_t = t2 & 1;
    }
    const int m0 = m_t * 256, n0 = n_t * 256;

    const f32x4 vzero = {0.f, 0.f, 0.f, 0.f};
    f32x4 acc[8][4];
#pragma unroll
    for (int i = 0; i < 8; i++)
#pragma unroll
        for (int j = 0; j < 4; j++) acc[i][j] = vzero;

    const int srow = lane >> 2;                         // 0..15
    const int scol = (((lane & 3) + ((srow >> 1) & 3)) & 3) * 8;
    const int csw  = ((quad - ((r >> 1) & 3)) & 3) * 8;

    for (int k0 = 0; k0 < K; k0 += 32) {
        __syncthreads();
        // A: 256 rows; B: 256 rows (= output cols). Each wave covers 32 rows
        // of each in 2 chunks of 16 -> 8 gll instrs per wave per K-tile.
#pragma unroll
        for (int tt = 0; tt < 2; tt++) {
            int base = wave * 32 + tt * 16;
            int rr = base + srow;
            int lb = base * 32;
            size_t ga = (size_t)(m0 + rr) * K + k0 + scol;
            size_t gb = (size_t)(n0 + rr) * K + k0 + scol;
            async_copy16(Ahi + ga, &As_h[lb]);
            async_copy16(Alo + ga, &As_l[lb]);
            async_copy16(Bhi + gb, &Bs_h[lb]);
            async_copy16(Blo + gb, &Bs_l[lb]);
        }
        __syncthreads();

        bf16x8 bh[4], bl[4];
#pragma unroll
        for (int j = 0; j < 4; j++) {
            int bofs = (wn * 64 + j * 16 + r) * 32 + csw;
            bh[j] = *(const bf16x8*)&Bs_h[bofs];
            bl[j] = *(const bf16x8*)&Bs_l[bofs];
        }
#pragma unroll
        for (int ih = 0; ih < 2; ih++) {
            bf16x8 ah[4], al[4];
#pragma unroll
            for (int i = 0; i < 4; i++) {
                int aofs = (wm * 128 + ih * 64 + i * 16 + r) * 32 + csw;
                ah[i] = *(const bf16x8*)&As_h[aofs];
                al[i] = *(const bf16x8*)&As_l[aofs];
            }
#pragma unroll
            for (int i = 0; i < 4; i++)
#pragma unroll
                for (int j = 0; j < 4; j++) {
                    int ii = ih * 4 + i;
                    acc[ii][j] = __builtin_amdgcn_mfma_f32_16x16x32_bf16(ah[i], bh[j], acc[ii][j], 0, 0, 0);
                    acc[ii][j] = __builtin_amdgcn_mfma_f32_16x16x32_bf16(ah[i], bl[j], acc[ii][j], 0, 0, 0);
                    acc[ii][j] = __builtin_amdgcn_mfma_f32_16x16x32_bf16(al[i], bh[j], acc[ii][j], 0, 0, 0);
                }
        }
    }

    float bia[4], sc[4], sh[4];
#pragma unroll
    for (int j = 0; j < 4; j++) {
        int col = n0 + wn * 64 + j * 16 + r;
        bia[j] = bias[col];
        if (mode == 2) {
            float g = bn_g[col], bb = bn_b[col], mm = bn_m[col], vv = bn_v[col];
            sc[j] = g * rsqrtf(vv + BN_EPS);
            sh[j] = bb - mm * sc[j];
        } else { sc[j] = 1.f; sh[j] = 0.f; }
    }
#pragma unroll
    for (int ii = 0; ii < 8; ii++) {
#pragma unroll
        for (int rg = 0; rg < 4; rg++) {
            int row = m0 + wm * 128 + ii * 16 + quad * 4 + rg;
            if (row >= N_NODES) continue;
#pragma unroll
            for (int j = 0; j < 4; j++) {
                int col = n0 + wn * 64 + j * 16 + r;
                float v = acc[ii][j][rg] + bia[j];
                if (mode >= 1) v = fmaxf(v, 0.f);
                if (mode == 2) v = v * sc[j] + sh[j];
                size_t oix = (size_t)row * HIDDEN + col;
                if (Cf) {
                    Cf[oix] = v;
                } else {
                    ushort_t hb = f2b(v);
                    ushort_t lb = f2b(v - b2f(hb));
                    Chi[oix] = hb;
                    Clo[oix] = lb;
                }
            }
        }
    }
}

// ---------------------------------------------------------------------------
// K=64 specialized GEMM: whole K staged once in 64 KB LDS, ONE barrier total.
// ---------------------------------------------------------------------------
__global__ __launch_bounds__(256) void gemm_k64_kernel(
    const ushort_t* __restrict__ Ahi, const ushort_t* __restrict__ Alo,
    const ushort_t* __restrict__ Bhi, const ushort_t* __restrict__ Blo,
    const float* __restrict__ bias,
    ushort_t* __restrict__ Chi, ushort_t* __restrict__ Clo) {
    const int K = 64;
    __shared__ ushort_t As_h[128 * 64];
    __shared__ ushort_t As_l[128 * 64];
    __shared__ ushort_t Bs_h[128 * 64];
    __shared__ ushort_t Bs_l[128 * 64];

    const int tid  = threadIdx.x;
    const int wave = tid >> 6, lane = tid & 63;
    const int wm = wave >> 1, wn = wave & 1;
    const int quad = lane >> 4, r = lane & 15;

    int idx = blockIdx.x, m_t, n_t;
    if (idx < FULLGRP) {
        m_t = (idx >> 5) * 8 + (idx & 7);
        n_t = (idx >> 3) & 3;
    } else {
        int t = idx - FULLGRP;
        m_t = (FULLGRP >> 2) + (t >> 2);
        n_t = t & 3;
    }
    const int m0 = m_t * 128, n0 = n_t * 128;

    const int srow8 = lane >> 3;                       // 0..7
    const int sc8   = (((lane & 7) - srow8) & 7) * 8;  // src elem offset
#pragma unroll
    for (int t = 0; t < 4; t++) {
        int base = wave * 32 + t * 8;
        int rr = base + srow8;
        int lbase = base * 64;
        size_t ga = (size_t)(m0 + rr) * K + sc8;
        size_t gb = (size_t)(n0 + rr) * K + sc8;
        async_copy16(Ahi + ga, &As_h[lbase]);
        async_copy16(Alo + ga, &As_l[lbase]);
        async_copy16(Bhi + gb, &Bs_h[lbase]);
        async_copy16(Blo + gb, &Bs_l[lbase]);
    }
    __syncthreads();   // single barrier: drain DMA, then compute

    const f32x4 vzero = {0.f, 0.f, 0.f, 0.f};
    f32x4 acc[4][4];
#pragma unroll
    for (int i = 0; i < 4; i++)
#pragma unroll
        for (int j = 0; j < 4; j++) acc[i][j] = vzero;

#pragma unroll
    for (int ks = 0; ks < 2; ks++) {           // two 32-k chunks
        bf16x8 ah[4], al[4], bh[4], bl[4];
#pragma unroll
        for (int i = 0; i < 4; i++) {
            int ra = wm * 64 + i * 16 + r;
            int rb = wn * 64 + i * 16 + r;
            int ca = ((quad + ks * 4 + (ra & 7)) & 7) * 8;
            int cb = ((quad + ks * 4 + (rb & 7)) & 7) * 8;
            ah[i] = *(const bf16x8*)&As_h[ra * 64 + ca];
            al[i] = *(const bf16x8*)&As_l[ra * 64 + ca];
            bh[i] = *(const bf16x8*)&Bs_h[rb * 64 + cb];
            bl[i] = *(const bf16x8*)&Bs_l[rb * 64 + cb];
        }
#pragma unroll
        for (int i = 0; i < 4; i++)
#pragma unroll
            for (int j = 0; j < 4; j++) {
                acc[i][j] = __builtin_amdgcn_mfma_f32_16x16x32_bf16(ah[i], bh[j], acc[i][j], 0, 0, 0);
                acc[i][j] = __builtin_amdgcn_mfma_f32_16x16x32_bf16(ah[i], bl[j], acc[i][j], 0, 0, 0);
                acc[i][j] = __builtin_amdgcn_mfma_f32_16x16x32_bf16(al[i], bh[j], acc[i][j], 0, 0, 0);
            }
    }

    float bia[4];
#pragma unroll
    for (int j = 0; j < 4; j++) bia[j] = bias[n0 + wn * 64 + j * 16 + r];
#pragma unroll
    for (int i = 0; i < 4; i++) {
#pragma unroll
        for (int rg = 0; rg < 4; rg++) {
            int row = m0 + wm * 64 + i * 16 + quad * 4 + rg;
            if (row >= N_NODES) continue;
#pragma unroll
            for (int j = 0; j < 4; j++) {
                int col = n0 + wn * 64 + j * 16 + r;
                float v = fmaxf(acc[i][j][rg] + bia[j], 0.f);
                size_t oix = (size_t)row * HIDDEN + col;
                ushort_t hb = f2b(v);
                ushort_t lb = f2b(v - b2f(hb));
                Chi[oix] = hb;
                Clo[oix] = lb;
            }
        }
    }
}

// ---------------------------------------------------------------------------
// out[t] = (h[a_t] * h[b_t]) @ fc2_W + fc2_b ; one wave per train edge.
// ---------------------------------------------------------------------------
__global__ __launch_bounds__(256) void fc2_kernel(
    const float* __restrict__ h, const int* __restrict__ ei,
    const int* __restrict__ teid, const float* __restrict__ W,
    const float* __restrict__ bias, float* __restrict__ out) {
    __shared__ float Ws[HIDDEN * N_CLASS];
    __shared__ float bs[N_CLASS];
    for (int i = threadIdx.x; i < HIDDEN * N_CLASS; i += blockDim.x) Ws[i] = W[i];
    if (threadIdx.x < N_CLASS) bs[threadIdx.x] = bias[threadIdx.x];
    __syncthreads();

    int wave = threadIdx.x >> 6;
    int lane = threadIdx.x & 63;
    int t = blockIdx.x * 4 + wave;
    if (t >= N_TRAIN) return;

    int e = teid[t];
    int a = ei[e];
    int b = ei[N_EDGES + e];
    const float* xa = h + (size_t)a * HIDDEN;
    const float* xb = h + (size_t)b * HIDDEN;

    float acc[N_CLASS];
#pragma unroll
    for (int c = 0; c < N_CLASS; c++) acc[c] = 0.f;

    int j0 = lane * 8;
    float4 a0 = *(const float4*)&xa[j0];
    float4 a1 = *(const float4*)&xa[j0 + 4];
    float4 b0 = *(const float4*)&xb[j0];
    float4 b1 = *(const float4*)&xb[j0 + 4];
    float p[8] = {a0.x * b0.x, a0.y * b0.y, a0.z * b0.z, a0.w * b0.w,
                  a1.x * b1.x, a1.y * b1.y, a1.z * b1.z, a1.w * b1.w};
#pragma unroll
    for (int jj = 0; jj < 8; jj++) {
        const float* wrow = &Ws[(j0 + jj) * N_CLASS];
#pragma unroll
        for (int c = 0; c < N_CLASS; c++) acc[c] = fmaf(p[jj], wrow[c], acc[c]);
    }
#pragma unroll
    for (int c = 0; c < N_CLASS; c++) {
        float v = acc[c];
        for (int off = 32; off > 0; off >>= 1) v += __shfl_down(v, off, 64);
        if (lane == 0) out[(size_t)t * N_CLASS + c] = v + bs[c];
    }
}

// ---------------------------------------------------------------------------
extern "C" void kernel_launch(void* const* d_in, const int* in_sizes, int n_in,
                              void* d_out, int out_size, void* d_ws, size_t ws_size,
                              hipStream_t stream) {
    const float* x      = (const float*)d_in[0];
    const int*   ei     = (const int*)d_in[1];
    const int*   teid   = (const int*)d_in[2];
    const float* W1     = (const float*)d_in[3];
    const float* b1     = (const float*)d_in[4];
    const float* W2     = (const float*)d_in[5];
    const float* b2     = (const float*)d_in[6];
    const float* W3     = (const float*)d_in[7];
    const float* b3     = (const float*)d_in[8];
    const float* bn1_g  = (const float*)d_in[9];
    const float* bn1_b  = (const float*)d_in[10];
    const float* bn1_m  = (const float*)d_in[11];
    const float* bn1_v  = (const float*)d_in[12];
    const float* eps1   = (const float*)d_in[13];
    const float* W4     = (const float*)d_in[14];
    const float* b4     = (const float*)d_in[15];
    const float* bn2_g  = (const float*)d_in[16];
    const float* bn2_b  = (const float*)d_in[17];
    const float* bn2_m  = (const float*)d_in[18];
    const float* bn2_v  = (const float*)d_in[19];
    const float* eps2   = (const float*)d_in[20];
    const float* lin1_W = (const float*)d_in[21];
    const float* lin1_b = (const float*)d_in[22];
    const float* lin2_W = (const float*)d_in[23];
    const float* lin2_b = (const float*)d_in[24];
    const float* fc2_W  = (const float*)d_in[25];
    const float* fc2_b  = (const float*)d_in[26];

    const size_t PLANE   = (size_t)MPAD * HIDDEN;
    const size_t PLANE64 = (size_t)MPAD * IN_F;

    ushort_t* R0h = (ushort_t*)d_ws;
    ushort_t* R0l = R0h + PLANE;
    ushort_t* R1h = R0l + PLANE;
    ushort_t* R1l = R1h + PLANE;

    const size_t WSMALL = (size_t)HIDDEN * IN_F;
    const size_t WBIG   = (size_t)HIDDEN * HIDDEN;
    ushort_t* Wp   = R1l + PLANE;
    ushort_t* Wt1h = Wp;            ushort_t* Wt1l = Wt1h + WSMALL;
    ushort_t* Wt2h = Wt1l + WSMALL; ushort_t* Wt2l = Wt2h + WBIG;
    ushort_t* Wt3h = Wt2l + WBIG;   ushort_t* Wt3l = Wt3h + WBIG;
    ushort_t* Wt4h = Wt3l + WBIG;   ushort_t* Wt4l = Wt4h + WBIG;
    ushort_t* Wt5h = Wt4l + WBIG;   ushort_t* Wt5l = Wt5h + WBIG;
    ushort_t* Wt6h = Wt5l + WBIG;   ushort_t* Wt6l = Wt6h + WBIG;

    // CSR arrays (ints) after weights
    int* deg    = (int*)(Wt6l + WBIG);
    int* cursor = deg + N_NODES;
    int* rowptr = cursor + N_NODES;        // N_NODES + 1
    int* bsum   = rowptr + (N_NODES + 1);  // NBLK
    int* boff   = bsum + NBLK;             // NBLK
    int* adj    = boff + NBLK;             // N_EDGES

    // fp32 aliases
    float* F32_R0 = (float*)R0h;
    ushort_t* H0h = R1h;
    ushort_t* H0l = R1h + PLANE64;

    // ---- CSR build (decoupled scan) ----
    zero_kernel<<<(N_NODES + 255) / 256, 256, 0, stream>>>(deg, N_NODES);
    hist_kernel<<<(N_EDGES + 255) / 256, 256, 0, stream>>>(ei, deg);
    blocksum_kernel<<<NBLK, 256, 0, stream>>>(deg, bsum);
    scanbsum_kernel<<<1, 256, 0, stream>>>(bsum, boff);
    rowptr_kernel<<<NBLK, 256, 0, stream>>>(deg, boff, rowptr, cursor);
    scatter_kernel<<<(N_EDGES + 255) / 256, 256, 0, stream>>>(ei, cursor, adj);

    // ---- weight prep: one batched launch ----
    wtrans_all_kernel<<<dim3(16, 16, 6), 256, 0, stream>>>(W1, W2, W3, W4,
                                                           lin1_W, lin2_W, Wp);

    const int ngrid = MT * NT;     // 1564 blocks (K=64 kernel)
    int nwb = (N_NODES + 3) / 4;

    // ---- h0 = (1+eps1)*x + gather(x) -> H0 split ----
    gather64_kernel<<<nwb, 256, 0, stream>>>(x, rowptr, adj, eps1, H0h, H0l);

    // h1 = relu(h0 @ W1 + b1) -> R0 split  (K=64 single-stage kernel)
    gemm_k64_kernel<<<ngrid, 256, 0, stream>>>(H0h, H0l, Wt1h, Wt1l, b1, R0h, R0l);
    // h2 = relu(h1 @ W2 + b2) -> R1 split
    gemm_split2x256_kernel<<<NG3, 512, 0, stream>>>(R0h, R0l, Wt2h, Wt2l, b2,
        nullptr, R1h, R1l, 1, nullptr, nullptr, nullptr, nullptr);
    // h3 = bn1(relu(h2 @ W3 + b3)) -> F32_R0
    gemm_split2x256_kernel<<<NG3, 512, 0, stream>>>(R1h, R1l, Wt3h, Wt3l, b3,
        F32_R0, nullptr, nullptr, 2, bn1_g, bn1_b, bn1_m, bn1_v);

    // ---- h4 = (1+eps2)*h3 + gather(h3) -> R1 split (2 waves/node) ----
    gather512_kernel<<<(N_NODES + 1) / 2, 256, 0, stream>>>(F32_R0, rowptr, adj,
                                                            eps2, R1h, R1l);

    // h5 = bn2(relu(h4 @ W4 + b4)) -> R0 split
    gemm_split2x256_kernel<<<NG3, 512, 0, stream>>>(R1h, R1l, Wt4h, Wt4l, b4,
        nullptr, R0h, R0l, 2, bn2_g, bn2_b, bn2_m, bn2_v);
    // h6 = relu(h5 @ lin1_W + lin1_b) -> R1 split
    gemm_split2x256_kernel<<<NG3, 512, 0, stream>>>(R0h, R0l, Wt5h, Wt5l, lin1_b,
        nullptr, R1h, R1l, 1, nullptr, nullptr, nullptr, nullptr);
    // h7 = h6 @ lin2_W + lin2_b -> F32_R0
    gemm_split2x256_kernel<<<NG3, 512, 0, stream>>>(R1h, R1l, Wt6h, Wt6l, lin2_b,
        F32_R0, nullptr, nullptr, 0, nullptr, nullptr, nullptr, nullptr);

    // head
    fc2_kernel<<<(N_TRAIN + 3) / 4, 256, 0, stream>>>(F32_R0, ei, teid, fc2_W, fc2_b,
                                                      (float*)d_out);
}

// Round 6
// 843.141 us; speedup vs baseline: 4.5764x; 4.5764x over previous
//
#include <hip/hip_runtime.h>

#define N_NODES 50000
#define MPAD    50048           // N_NODES rounded up to 128
#define IN_F    64
#define HIDDEN  512
#define N_EDGES 160000
#define N_TRAIN 80000
#define N_CLASS 7
#define BN_EPS  1e-5f

#define MT      (MPAD / 128)    // 391 m-tiles
#define NT      4               // 128-col n-tiles (K=64 kernel)
#define FULLGRP ((MT / 8) * 32) // 1536
#define NBLK    ((N_NODES + 255) / 256)   // 196 scan blocks

// 128x256 tiling for the K=512 GEMM: 391 m-tiles x 2 n-tiles
#define NT4     2
#define FULLG4  ((MT / 8) * 16)           // 768 (48 groups of 8m x 2n)
#define NG4     (MT * NT4)                // 782 blocks

typedef short  bf16x8 __attribute__((ext_vector_type(8)));
typedef float  f32x4  __attribute__((ext_vector_type(4)));
typedef unsigned short ushort_t;

// ---- bf16 helpers (manual RNE; values are finite) -------------------------
__device__ __forceinline__ ushort_t f2b(float v) {
    union { float f; unsigned int u; } c; c.f = v;
    unsigned int x = c.u;
    unsigned int r = (x + 0x7FFFu + ((x >> 16) & 1u)) >> 16;
    return (ushort_t)r;
}
__device__ __forceinline__ float b2f(ushort_t b) {
    union { unsigned int u; float f; } c; c.u = ((unsigned int)b) << 16;
    return c.f;
}

// ---- async global->LDS, 16B per lane (dst = wave-uniform base + lane*16) --
__device__ __forceinline__ void async_copy16(const void* g, void* l) {
    __builtin_amdgcn_global_load_lds(
        (const __attribute__((address_space(1))) void*)g,
        (__attribute__((address_space(3))) void*)l, 16, 0, 0);
}

// ===========================================================================
// CSR build: zero -> histogram(dst) -> decoupled scan -> scatter src ids
// ===========================================================================
__global__ void zero_kernel(int* __restrict__ p, int n) {
    int i = blockIdx.x * blockDim.x + threadIdx.x;
    if (i < n) p[i] = 0;
}

__global__ void hist_kernel(const int* __restrict__ ei, int* __restrict__ deg) {
    int e = blockIdx.x * blockDim.x + threadIdx.x;
    if (e >= N_EDGES) return;
    atomicAdd(&deg[ei[N_EDGES + e]], 1);
}

__global__ __launch_bounds__(256) void blocksum_kernel(const int* __restrict__ deg,
                                                       int* __restrict__ bsum) {
    __shared__ int s[256];
    int i = blockIdx.x * 256 + threadIdx.x;
    s[threadIdx.x] = (i < N_NODES) ? deg[i] : 0;
    __syncthreads();
    for (int off = 128; off > 0; off >>= 1) {
        if (threadIdx.x < off) s[threadIdx.x] += s[threadIdx.x + off];
        __syncthreads();
    }
    if (threadIdx.x == 0) bsum[blockIdx.x] = s[0];
}

__global__ __launch_bounds__(256) void scanbsum_kernel(const int* __restrict__ bsum,
                                                       int* __restrict__ boff) {
    __shared__ int s[256];
    int tid = threadIdx.x;
    s[tid] = (tid < NBLK) ? bsum[tid] : 0;
    __syncthreads();
    for (int off = 1; off < 256; off <<= 1) {
        int t = (tid >= off) ? s[tid - off] : 0;
        __syncthreads();
        s[tid] += t;
        __syncthreads();
    }
    if (tid < NBLK) boff[tid] = (tid == 0) ? 0 : s[tid - 1];
}

__global__ __launch_bounds__(256) void rowptr_kernel(const int* __restrict__ deg,
                                                     const int* __restrict__ boff,
                                                     int* __restrict__ rowptr,
                                                     int* __restrict__ cursor) {
    __shared__ int s[256];
    int tid = threadIdx.x;
    int i = blockIdx.x * 256 + tid;
    int d = (i < N_NODES) ? deg[i] : 0;
    s[tid] = d;
    __syncthreads();
    for (int off = 1; off < 256; off <<= 1) {
        int t = (tid >= off) ? s[tid - off] : 0;
        __syncthreads();
        s[tid] += t;
        __syncthreads();
    }
    int incl = s[tid] + boff[blockIdx.x];
    if (i < N_NODES) {
        rowptr[i + 1] = incl;
        cursor[i] = incl - d;   // exclusive prefix = row start
    }
    if (i == 0) rowptr[0] = 0;
}

__global__ void scatter_kernel(const int* __restrict__ ei,
                               int* __restrict__ cursor, int* __restrict__ adj) {
    int e = blockIdx.x * blockDim.x + threadIdx.x;
    if (e >= N_EDGES) return;
    int src = ei[e], dst = ei[N_EDGES + e];
    int pos = atomicAdd(&cursor[dst], 1);
    adj[pos] = src;
}

// ===========================================================================
// Gather aggregation (CSR), fused scale + split-bf16 output.
// ===========================================================================
__global__ __launch_bounds__(256) void gather64_kernel(
    const float* __restrict__ x, const int* __restrict__ rowptr,
    const int* __restrict__ adj, const float* __restrict__ epsp,
    ushort_t* __restrict__ hi, ushort_t* __restrict__ lo) {
    int wave = threadIdx.x >> 6, lane = threadIdx.x & 63;
    int n = blockIdx.x * 4 + wave;
    if (n >= N_NODES) return;
    float s = 1.0f + *epsp;
    float sum = s * x[(size_t)n * IN_F + lane];
    int beg = rowptr[n], end = rowptr[n + 1];
    for (int k = beg; k < end; k++) {
        sum += x[(size_t)adj[k] * IN_F + lane];
    }
    ushort_t hb = f2b(sum);
    ushort_t lb = f2b(sum - b2f(hb));
    hi[(size_t)n * IN_F + lane] = hb;
    lo[(size_t)n * IN_F + lane] = lb;
}

__global__ __launch_bounds__(256) void gather512_kernel(
    const float* __restrict__ h, const int* __restrict__ rowptr,
    const int* __restrict__ adj, const float* __restrict__ epsp,
    ushort_t* __restrict__ hi, ushort_t* __restrict__ lo) {
    int wave = threadIdx.x >> 6, lane = threadIdx.x & 63;
    int n = blockIdx.x * 2 + (wave >> 1);
    if (n >= N_NODES) return;
    float s = 1.0f + *epsp;
    const int f = (wave & 1) * 256 + lane * 4;
    float4 a = *(const float4*)&h[(size_t)n * HIDDEN + f];
    float sum[4] = {s * a.x, s * a.y, s * a.z, s * a.w};
    int beg = rowptr[n], end = rowptr[n + 1];
    for (int k = beg; k < end; k++) {
        float4 b = *(const float4*)&h[(size_t)adj[k] * HIDDEN + f];
        sum[0] += b.x; sum[1] += b.y; sum[2] += b.z; sum[3] += b.w;
    }
    ushort_t h4[4], l4[4];
#pragma unroll
    for (int j = 0; j < 4; j++) {
        h4[j] = f2b(sum[j]);
        l4[j] = f2b(sum[j] - b2f(h4[j]));
    }
    *(ushort4*)&hi[(size_t)n * HIDDEN + f] = make_ushort4(h4[0], h4[1], h4[2], h4[3]);
    *(ushort4*)&lo[(size_t)n * HIDDEN + f] = make_ushort4(l4[0], l4[1], l4[2], l4[3]);
}

// ---------------------------------------------------------------------------
// Batched weight prep: all 6 W[K][512] fp32 -> Wt_hi/lo[512][K] bf16.
// ---------------------------------------------------------------------------
__global__ void wtrans_all_kernel(const float* __restrict__ w0,
                                  const float* __restrict__ w1,
                                  const float* __restrict__ w2,
                                  const float* __restrict__ w3,
                                  const float* __restrict__ w4,
                                  const float* __restrict__ w5,
                                  ushort_t* __restrict__ Wp) {
    const size_t WSMALL = (size_t)HIDDEN * IN_F;
    const size_t WBIG   = (size_t)HIDDEN * HIDDEN;
    int z = blockIdx.z;
    const float* W = (z == 0) ? w0 : (z == 1) ? w1 : (z == 2) ? w2
                   : (z == 3) ? w3 : (z == 4) ? w4 : w5;
    int K = (z == 0) ? IN_F : HIDDEN;
    size_t off_h = (z == 0) ? 0 : 2 * WSMALL + (size_t)(z - 1) * 2 * WBIG;
    ushort_t* Whi = Wp + off_h;
    ushort_t* Wlo = Whi + ((z == 0) ? WSMALL : WBIG);

    __shared__ float t[32][33];
    int tx = threadIdx.x & 31, ty = threadIdx.x >> 5;   // ty 0..7
    int nb = blockIdx.x * 32, kb = blockIdx.y * 32;
    if (kb >= K) return;
#pragma unroll
    for (int i = 0; i < 4; i++) {
        int k = kb + ty + i * 8;
        t[ty + i * 8][tx] = W[(size_t)k * HIDDEN + nb + tx];
    }
    __syncthreads();
#pragma unroll
    for (int i = 0; i < 4; i++) {
        int n = nb + ty + i * 8;
        int k = kb + tx;
        float v = t[tx][ty + i * 8];
        ushort_t hb = f2b(v);
        ushort_t lb = f2b(v - b2f(hb));
        Whi[(size_t)n * K + k] = hb;
        Wlo[(size_t)n * K + k] = lb;
    }
}

// ---------------------------------------------------------------------------
// K=512 split-bf16 GEMM, BM=128 x BN=256, 4 waves (256 thr).
// Wave grid 1x4: each wave owns 128 rows x 64 cols (acc[8][4]) — IDENTICAL
// per-wave register footprint to R4's proven 124-VGPR layout; launch_bounds
// (256,2) keeps the 256-VGPR cap (R5's (512,4) capped at 128 and spilled the
// 128-reg accumulator to scratch: VGPR_Count=64, 2.75 GB scratch traffic,
// 716 µs — the whole regression).
// Traffic (model a=0.241 µs/MB A-panel/L3, b=0.078 µs/MB B-weights/L2,
// calibrated on R0/R4): BN=128->256 halves the expensive A term:
// A 205 MB + B 410 MB -> ~81 µs predicted. 48 KB LDS, 782 balanced blocks,
// 2-3 blocks/CU residency (the m114 cross-block overlap R0/R4 rely on).
// Schedule = R0's proven single-buffer 2-barrier loop.
// ---------------------------------------------------------------------------
__global__ __launch_bounds__(256, 2) void gemm_split128x256_kernel(
    const ushort_t* __restrict__ Ahi, const ushort_t* __restrict__ Alo,
    const ushort_t* __restrict__ Bhi, const ushort_t* __restrict__ Blo,
    const float* __restrict__ bias,
    float* __restrict__ Cf, ushort_t* __restrict__ Chi, ushort_t* __restrict__ Clo,
    int mode,
    const float* __restrict__ bn_g, const float* __restrict__ bn_b,
    const float* __restrict__ bn_m, const float* __restrict__ bn_v) {
    const int K = HIDDEN;            // 512
    __shared__ ushort_t As_h[128 * 32];   //  8 KB
    __shared__ ushort_t As_l[128 * 32];   //  8 KB
    __shared__ ushort_t Bs_h[256 * 32];   // 16 KB
    __shared__ ushort_t Bs_l[256 * 32];   // 16 KB  -> 48 KB total

    const int tid  = threadIdx.x;
    const int wave = tid >> 6, lane = tid & 63;   // wave = n-slice owner
    const int quad = lane >> 4, r = lane & 15;

    int idx = blockIdx.x, m_t, n_t;
    if (idx < FULLG4) {                 // groups of 8 m-tiles x 2 n-tiles
        m_t = (idx >> 4) * 8 + (idx & 7);
        n_t = (idx >> 3) & 1;
    } else {
        int t2 = idx - FULLG4;          // tail: m-tiles 384..390 x 2
        m_t = 384 + (t2 >> 1);
        n_t = t2 & 1;
    }
    const int m0 = m_t * 128, n0 = n_t * 256;

    const f32x4 vzero = {0.f, 0.f, 0.f, 0.f};
    f32x4 acc[8][4];
#pragma unroll
    for (int i = 0; i < 8; i++)
#pragma unroll
        for (int j = 0; j < 4; j++) acc[i][j] = vzero;

    const int srow = lane >> 2;                         // 0..15
    const int scol = (((lane & 3) + ((srow >> 1) & 3)) & 3) * 8;
    const int csw  = ((quad - ((r >> 1) & 3)) & 3) * 8;

    for (int k0 = 0; k0 < K; k0 += 32) {
        __syncthreads();
        // stage A: 128 rows; wave covers 32 rows in 2 chunks of 16
#pragma unroll
        for (int tt = 0; tt < 2; tt++) {
            int base = wave * 32 + tt * 16;
            int rr = base + srow;
            int lba = base * 32;
            size_t ga = (size_t)(m0 + rr) * K + k0 + scol;
            async_copy16(Ahi + ga, &As_h[lba]);
            async_copy16(Alo + ga, &As_l[lba]);
        }
        // stage B: 256 rows (= output cols); wave covers 64 rows in 4 chunks
#pragma unroll
        for (int tt = 0; tt < 4; tt++) {
            int base = wave * 64 + tt * 16;
            int rr = base + srow;
            int lbb = base * 32;
            size_t gb = (size_t)(n0 + rr) * K + k0 + scol;
            async_copy16(Bhi + gb, &Bs_h[lbb]);
            async_copy16(Blo + gb, &Bs_l[lbb]);
        }
        __syncthreads();

        bf16x8 bh[4], bl[4];
#pragma unroll
        for (int j = 0; j < 4; j++) {
            int bofs = (wave * 64 + j * 16 + r) * 32 + csw;
            bh[j] = *(const bf16x8*)&Bs_h[bofs];
            bl[j] = *(const bf16x8*)&Bs_l[bofs];
        }
#pragma unroll
        for (int ih = 0; ih < 2; ih++) {
            bf16x8 ah[4], al[4];
#pragma unroll
            for (int i = 0; i < 4; i++) {
                int aofs = (ih * 64 + i * 16 + r) * 32 + csw;
                ah[i] = *(const bf16x8*)&As_h[aofs];
                al[i] = *(const bf16x8*)&As_l[aofs];
            }
#pragma unroll
            for (int i = 0; i < 4; i++)
#pragma unroll
                for (int j = 0; j < 4; j++) {
                    int ii = ih * 4 + i;
                    acc[ii][j] = __builtin_amdgcn_mfma_f32_16x16x32_bf16(ah[i], bh[j], acc[ii][j], 0, 0, 0);
                    acc[ii][j] = __builtin_amdgcn_mfma_f32_16x16x32_bf16(ah[i], bl[j], acc[ii][j], 0, 0, 0);
                    acc[ii][j] = __builtin_amdgcn_mfma_f32_16x16x32_bf16(al[i], bh[j], acc[ii][j], 0, 0, 0);
                }
        }
    }

    float bia[4], sc[4], sh[4];
#pragma unroll
    for (int j = 0; j < 4; j++) {
        int col = n0 + wave * 64 + j * 16 + r;
        bia[j] = bias[col];
        if (mode == 2) {
            float g = bn_g[col], bb = bn_b[col], mm = bn_m[col], vv = bn_v[col];
            sc[j] = g * rsqrtf(vv + BN_EPS);
            sh[j] = bb - mm * sc[j];
        } else { sc[j] = 1.f; sh[j] = 0.f; }
    }
#pragma unroll
    for (int ii = 0; ii < 8; ii++) {
#pragma unroll
        for (int rg = 0; rg < 4; rg++) {
            int row = m0 + ii * 16 + quad * 4 + rg;
            if (row >= N_NODES) continue;
#pragma unroll
            for (int j = 0; j < 4; j++) {
                int col = n0 + wave * 64 + j * 16 + r;
                float v = acc[ii][j][rg] + bia[j];
                if (mode >= 1) v = fmaxf(v, 0.f);
                if (mode == 2) v = v * sc[j] + sh[j];
                size_t oix = (size_t)row * HIDDEN + col;
                if (Cf) {
                    Cf[oix] = v;
                } else {
                    ushort_t hb = f2b(v);
                    ushort_t lb = f2b(v - b2f(hb));
                    Chi[oix] = hb;
                    Clo[oix] = lb;
                }
            }
        }
    }
}

// ---------------------------------------------------------------------------
// K=64 specialized GEMM: whole K staged once in 64 KB LDS, ONE barrier total.
// ---------------------------------------------------------------------------
__global__ __launch_bounds__(256) void gemm_k64_kernel(
    const ushort_t* __restrict__ Ahi, const ushort_t* __restrict__ Alo,
    const ushort_t* __restrict__ Bhi, const ushort_t* __restrict__ Blo,
    const float* __restrict__ bias,
    ushort_t* __restrict__ Chi, ushort_t* __restrict__ Clo) {
    const int K = 64;
    __shared__ ushort_t As_h[128 * 64];
    __shared__ ushort_t As_l[128 * 64];
    __shared__ ushort_t Bs_h[128 * 64];
    __shared__ ushort_t Bs_l[128 * 64];

    const int tid  = threadIdx.x;
    const int wave = tid >> 6, lane = tid & 63;
    const int wm = wave >> 1, wn = wave & 1;
    const int quad = lane >> 4, r = lane & 15;

    int idx = blockIdx.x, m_t, n_t;
    if (idx < FULLGRP) {
        m_t = (idx >> 5) * 8 + (idx & 7);
        n_t = (idx >> 3) & 3;
    } else {
        int t = idx - FULLGRP;
        m_t = (FULLGRP >> 2) + (t >> 2);
        n_t = t & 3;
    }
    const int m0 = m_t * 128, n0 = n_t * 128;

    const int srow8 = lane >> 3;                       // 0..7
    const int sc8   = (((lane & 7) - srow8) & 7) * 8;  // src elem offset
#pragma unroll
    for (int t = 0; t < 4; t++) {
        int base = wave * 32 + t * 8;
        int rr = base + srow8;
        int lbase = base * 64;
        size_t ga = (size_t)(m0 + rr) * K + sc8;
        size_t gb = (size_t)(n0 + rr) * K + sc8;
        async_copy16(Ahi + ga, &As_h[lbase]);
        async_copy16(Alo + ga, &As_l[lbase]);
        async_copy16(Bhi + gb, &Bs_h[lbase]);
        async_copy16(Blo + gb, &Bs_l[lbase]);
    }
    __syncthreads();   // single barrier: drain DMA, then compute

    const f32x4 vzero = {0.f, 0.f, 0.f, 0.f};
    f32x4 acc[4][4];
#pragma unroll
    for (int i = 0; i < 4; i++)
#pragma unroll
        for (int j = 0; j < 4; j++) acc[i][j] = vzero;

#pragma unroll
    for (int ks = 0; ks < 2; ks++) {           // two 32-k chunks
        bf16x8 ah[4], al[4], bh[4], bl[4];
#pragma unroll
        for (int i = 0; i < 4; i++) {
            int ra = wm * 64 + i * 16 + r;
            int rb = wn * 64 + i * 16 + r;
            int ca = ((quad + ks * 4 + (ra & 7)) & 7) * 8;
            int cb = ((quad + ks * 4 + (rb & 7)) & 7) * 8;
            ah[i] = *(const bf16x8*)&As_h[ra * 64 + ca];
            al[i] = *(const bf16x8*)&As_l[ra * 64 + ca];
            bh[i] = *(const bf16x8*)&Bs_h[rb * 64 + cb];
            bl[i] = *(const bf16x8*)&Bs_l[rb * 64 + cb];
        }
#pragma unroll
        for (int i = 0; i < 4; i++)
#pragma unroll
            for (int j = 0; j < 4; j++) {
                acc[i][j] = __builtin_amdgcn_mfma_f32_16x16x32_bf16(ah[i], bh[j], acc[i][j], 0, 0, 0);
                acc[i][j] = __builtin_amdgcn_mfma_f32_16x16x32_bf16(ah[i], bl[j], acc[i][j], 0, 0, 0);
                acc[i][j] = __builtin_amdgcn_mfma_f32_16x16x32_bf16(al[i], bh[j], acc[i][j], 0, 0, 0);
            }
    }

    float bia[4];
#pragma unroll
    for (int j = 0; j < 4; j++) bia[j] = bias[n0 + wn * 64 + j * 16 + r];
#pragma unroll
    for (int i = 0; i < 4; i++) {
#pragma unroll
        for (int rg = 0; rg < 4; rg++) {
            int row = m0 + wm * 64 + i * 16 + quad * 4 + rg;
            if (row >= N_NODES) continue;
#pragma unroll
            for (int j = 0; j < 4; j++) {
                int col = n0 + wn * 64 + j * 16 + r;
                float v = fmaxf(acc[i][j][rg] + bia[j], 0.f);
                size_t oix = (size_t)row * HIDDEN + col;
                ushort_t hb = f2b(v);
                ushort_t lb = f2b(v - b2f(hb));
                Chi[oix] = hb;
                Clo[oix] = lb;
            }
        }
    }
}

// ---------------------------------------------------------------------------
// out[t] = (h[a_t] * h[b_t]) @ fc2_W + fc2_b ; one wave per train edge.
// ---------------------------------------------------------------------------
__global__ __launch_bounds__(256) void fc2_kernel(
    const float* __restrict__ h, const int* __restrict__ ei,
    const int* __restrict__ teid, const float* __restrict__ W,
    const float* __restrict__ bias, float* __restrict__ out) {
    __shared__ float Ws[HIDDEN * N_CLASS];
    __shared__ float bs[N_CLASS];
    for (int i = threadIdx.x; i < HIDDEN * N_CLASS; i += blockDim.x) Ws[i] = W[i];
    if (threadIdx.x < N_CLASS) bs[threadIdx.x] = bias[threadIdx.x];
    __syncthreads();

    int wave = threadIdx.x >> 6;
    int lane = threadIdx.x & 63;
    int t = blockIdx.x * 4 + wave;
    if (t >= N_TRAIN) return;

    int e = teid[t];
    int a = ei[e];
    int b = ei[N_EDGES + e];
    const float* xa = h + (size_t)a * HIDDEN;
    const float* xb = h + (size_t)b * HIDDEN;

    float acc[N_CLASS];
#pragma unroll
    for (int c = 0; c < N_CLASS; c++) acc[c] = 0.f;

    int j0 = lane * 8;
    float4 a0 = *(const float4*)&xa[j0];
    float4 a1 = *(const float4*)&xa[j0 + 4];
    float4 b0 = *(const float4*)&xb[j0];
    float4 b1 = *(const float4*)&xb[j0 + 4];
    float p[8] = {a0.x * b0.x, a0.y * b0.y, a0.z * b0.z, a0.w * b0.w,
                  a1.x * b1.x, a1.y * b1.y, a1.z * b1.z, a1.w * b1.w};
#pragma unroll
    for (int jj = 0; jj < 8; jj++) {
        const float* wrow = &Ws[(j0 + jj) * N_CLASS];
#pragma unroll
        for (int c = 0; c < N_CLASS; c++) acc[c] = fmaf(p[jj], wrow[c], acc[c]);
    }
#pragma unroll
    for (int c = 0; c < N_CLASS; c++) {
        float v = acc[c];
        for (int off = 32; off > 0; off >>= 1) v += __shfl_down(v, off, 64);
        if (lane == 0) out[(size_t)t * N_CLASS + c] = v + bs[c];
    }
}

// ---------------------------------------------------------------------------
extern "C" void kernel_launch(void* const* d_in, const int* in_sizes, int n_in,
                              void* d_out, int out_size, void* d_ws, size_t ws_size,
                              hipStream_t stream) {
    const float* x      = (const float*)d_in[0];
    const int*   ei     = (const int*)d_in[1];
    const int*   teid   = (const int*)d_in[2];
    const float* W1     = (const float*)d_in[3];
    const float* b1     = (const float*)d_in[4];
    const float* W2     = (const float*)d_in[5];
    const float* b2     = (const float*)d_in[6];
    const float* W3     = (const float*)d_in[7];
    const float* b3     = (const float*)d_in[8];
    const float* bn1_g  = (const float*)d_in[9];
    const float* bn1_b  = (const float*)d_in[10];
    const float* bn1_m  = (const float*)d_in[11];
    const float* bn1_v  = (const float*)d_in[12];
    const float* eps1   = (const float*)d_in[13];
    const float* W4     = (const float*)d_in[14];
    const float* b4     = (const float*)d_in[15];
    const float* bn2_g  = (const float*)d_in[16];
    const float* bn2_b  = (const float*)d_in[17];
    const float* bn2_m  = (const float*)d_in[18];
    const float* bn2_v  = (const float*)d_in[19];
    const float* eps2   = (const float*)d_in[20];
    const float* lin1_W = (const float*)d_in[21];
    const float* lin1_b = (const float*)d_in[22];
    const float* lin2_W = (const float*)d_in[23];
    const float* lin2_b = (const float*)d_in[24];
    const float* fc2_W  = (const float*)d_in[25];
    const float* fc2_b  = (const float*)d_in[26];

    const size_t PLANE   = (size_t)MPAD * HIDDEN;
    const size_t PLANE64 = (size_t)MPAD * IN_F;

    ushort_t* R0h = (ushort_t*)d_ws;
    ushort_t* R0l = R0h + PLANE;
    ushort_t* R1h = R0l + PLANE;
    ushort_t* R1l = R1h + PLANE;

    const size_t WSMALL = (size_t)HIDDEN * IN_F;
    const size_t WBIG   = (size_t)HIDDEN * HIDDEN;
    ushort_t* Wp   = R1l + PLANE;
    ushort_t* Wt1h = Wp;            ushort_t* Wt1l = Wt1h + WSMALL;
    ushort_t* Wt2h = Wt1l + WSMALL; ushort_t* Wt2l = Wt2h + WBIG;
    ushort_t* Wt3h = Wt2l + WBIG;   ushort_t* Wt3l = Wt3h + WBIG;
    ushort_t* Wt4h = Wt3l + WBIG;   ushort_t* Wt4l = Wt4h + WBIG;
    ushort_t* Wt5h = Wt4l + WBIG;   ushort_t* Wt5l = Wt5h + WBIG;
    ushort_t* Wt6h = Wt5l + WBIG;   ushort_t* Wt6l = Wt6h + WBIG;

    // CSR arrays (ints) after weights
    int* deg    = (int*)(Wt6l + WBIG);
    int* cursor = deg + N_NODES;
    int* rowptr = cursor + N_NODES;        // N_NODES + 1
    int* bsum   = rowptr + (N_NODES + 1);  // NBLK
    int* boff   = bsum + NBLK;             // NBLK
    int* adj    = boff + NBLK;             // N_EDGES

    // fp32 aliases
    float* F32_R0 = (float*)R0h;
    ushort_t* H0h = R1h;
    ushort_t* H0l = R1h + PLANE64;

    // ---- CSR build (decoupled scan) ----
    zero_kernel<<<(N_NODES + 255) / 256, 256, 0, stream>>>(deg, N_NODES);
    hist_kernel<<<(N_EDGES + 255) / 256, 256, 0, stream>>>(ei, deg);
    blocksum_kernel<<<NBLK, 256, 0, stream>>>(deg, bsum);
    scanbsum_kernel<<<1, 256, 0, stream>>>(bsum, boff);
    rowptr_kernel<<<NBLK, 256, 0, stream>>>(deg, boff, rowptr, cursor);
    scatter_kernel<<<(N_EDGES + 255) / 256, 256, 0, stream>>>(ei, cursor, adj);

    // ---- weight prep: one batched launch ----
    wtrans_all_kernel<<<dim3(16, 16, 6), 256, 0, stream>>>(W1, W2, W3, W4,
                                                           lin1_W, lin2_W, Wp);

    const int ngrid = MT * NT;     // 1564 blocks (K=64 kernel)
    int nwb = (N_NODES + 3) / 4;

    // ---- h0 = (1+eps1)*x + gather(x) -> H0 split ----
    gather64_kernel<<<nwb, 256, 0, stream>>>(x, rowptr, adj, eps1, H0h, H0l);

    // h1 = relu(h0 @ W1 + b1) -> R0 split  (K=64 single-stage kernel)
    gemm_k64_kernel<<<ngrid, 256, 0, stream>>>(H0h, H0l, Wt1h, Wt1l, b1, R0h, R0l);
    // h2 = relu(h1 @ W2 + b2) -> R1 split
    gemm_split128x256_kernel<<<NG4, 256, 0, stream>>>(R0h, R0l, Wt2h, Wt2l, b2,
        nullptr, R1h, R1l, 1, nullptr, nullptr, nullptr, nullptr);
    // h3 = bn1(relu(h2 @ W3 + b3)) -> F32_R0
    gemm_split128x256_kernel<<<NG4, 256, 0, stream>>>(R1h, R1l, Wt3h, Wt3l, b3,
        F32_R0, nullptr, nullptr, 2, bn1_g, bn1_b, bn1_m, bn1_v);

    // ---- h4 = (1+eps2)*h3 + gather(h3) -> R1 split (2 waves/node) ----
    gather512_kernel<<<(N_NODES + 1) / 2, 256, 0, stream>>>(F32_R0, rowptr, adj,
                                                            eps2, R1h, R1l);

    // h5 = bn2(relu(h4 @ W4 + b4)) -> R0 split
    gemm_split128x256_kernel<<<NG4, 256, 0, stream>>>(R1h, R1l, Wt4h, Wt4l, b4,
        nullptr, R0h, R0l, 2, bn2_g, bn2_b, bn2_m, bn2_v);
    // h6 = relu(h5 @ lin1_W + lin1_b) -> R1 split
    gemm_split128x256_kernel<<<NG4, 256, 0, stream>>>(R0h, R0l, Wt5h, Wt5l, lin1_b,
        nullptr, R1h, R1l, 1, nullptr, nullptr, nullptr, nullptr);
    // h7 = h6 @ lin2_W + lin2_b -> F32_R0
    gemm_split128x256_kernel<<<NG4, 256, 0, stream>>>(R1h, R1l, Wt6h, Wt6l, lin2_b,
        F32_R0, nullptr, nullptr, 0, nullptr, nullptr, nullptr, nullptr);

    // head
    fc2_kernel<<<(N_TRAIN + 3) / 4, 256, 0, stream>>>(F32_R0, ei, teid, fc2_W, fc2_b,
                                                      (float*)d_out);
}